// Round 3
// baseline (874.421 us; speedup 1.0000x reference)
//
#include <hip/hip_runtime.h>

// YOLO_GNN on MI355X — round 3: ILP-fixed fused conv + parallelized tail.
// prep(+zero) -> convfused -> fcf -> fcclog(x4) -> top2 -> graph -> agg ->
// h1p(x8 partials) -> pfold -> gpart(x8) -> Mfold -> out.

typedef float f32x4 __attribute__((ext_vector_type(4)));

// ---------------- prep: zero pooled; transpose conv weights ----------------
// wt1: [k=(ci*3+ky)*3+kx][co32]; wt2: [pos=ky*3+kx][ci32][co64]
__global__ void k_prep(const float* __restrict__ w1, const float* __restrict__ w2,
                       float* __restrict__ wt1, float* __restrict__ wt2,
                       float* __restrict__ pooled) {
    int i = blockIdx.x * 256 + threadIdx.x;
    if (i < 4096) pooled[i] = 0.f;
    if (i < 864) {            // conv1: 32 co x 27 k
        int k = i >> 5, co = i & 31;
        wt1[i] = w1[co * 27 + k];
    }
    if (i < 18432) {          // conv2 pos-major
        int co = i & 63, t = i >> 6;
        int pos = t >> 5, ci = t & 31;
        wt2[i] = w2[co * 288 + ci * 9 + pos];
    }
}

// ---------------- fused conv1+ReLU -> LDS -> conv2+ReLU -> GAP ----------------
// Block = one conv2 row (oy) of image b; 256 threads.
__global__ __launch_bounds__(256) void k_convfused(const float* __restrict__ x,
                                                   const float* __restrict__ wt1,
                                                   const float* __restrict__ b1,
                                                   const float* __restrict__ wt2,
                                                   const float* __restrict__ b2,
                                                   float* __restrict__ pooled) {
    __shared__ float s[32][3][2][57];   // [ci][row][ix&1][ix>>1], 43776 B
    int oy = blockIdx.x;                // 0..55
    int b = blockIdx.y;                 // 0..63
    const float* xb = x + (size_t)b * 3 * 224 * 224;
    int tid = threadIdx.x;

    // stage: items i = ch*384 + r*128 + px  (ch,r wave-uniform; px<113 real)
#pragma unroll
    for (int k = 0; k < 3; k++) {
        int i = tid + k * 256;
        int px = i & 127;
        int r = (i >> 7) % 3;
        int ch = i / 384;               // co half, wave-uniform
        if (px < 113) {
            int iy = 2 * oy + r;
            if (iy < 112 && px < 112) {
                float acc[16];
#pragma unroll
                for (int j = 0; j < 16; j++) acc[j] = 0.f;
#pragma unroll
                for (int ky = 0; ky < 3; ky++) {
                    int yy = 2 * iy + ky;
#pragma unroll
                    for (int kx = 0; kx < 3; kx++) {
                        int xx = 2 * px + kx;
                        bool ok = (yy < 224) && (xx < 224);
#pragma unroll
                        for (int ci = 0; ci < 3; ci++) {
                            float v = ok ? xb[((size_t)ci * 224 + yy) * 224 + xx] : 0.f;
                            const float* w = wt1 + ((ci * 3 + ky) * 3 + kx) * 32 + ch * 16;
#pragma unroll
                            for (int j = 0; j < 16; j++) acc[j] = fmaf(v, w[j], acc[j]);
                        }
                    }
                }
#pragma unroll
                for (int j = 0; j < 16; j++)
                    s[ch * 16 + j][r][px & 1][px >> 1] = fmaxf(acc[j] + b1[ch * 16 + j], 0.f);
            } else {
#pragma unroll
                for (int j = 0; j < 16; j++)
                    s[ch * 16 + j][r][px & 1][px >> 1] = 0.f;
            }
        }
    }
    __syncthreads();

    // conv2: wave q -> co [16q,16q+16); lane -> px
    int q = __builtin_amdgcn_readfirstlane((int)(tid >> 6));
    int lane = tid & 63;
    bool pvld = lane < 56;
    int px = pvld ? lane : 55;
    float acc[16];
#pragma unroll
    for (int j = 0; j < 16; j++) acc[j] = 0.f;
#pragma unroll
    for (int pos = 0; pos < 9; pos++) {
        int ky = pos / 3, kx = pos % 3;
        int par = kx & 1, half = px + (kx >> 1);
        float v[32];
#pragma unroll
        for (int ci = 0; ci < 32; ci++) v[ci] = s[ci][ky][par][half];
        const float* w = wt2 + pos * 32 * 64 + q * 16;          // uniform -> s_load
#pragma unroll 4
        for (int ci = 0; ci < 32; ci++) {
#pragma unroll
            for (int j = 0; j < 16; j++) acc[j] = fmaf(v[ci], w[ci * 64 + j], acc[j]);
        }
    }
#pragma unroll
    for (int j = 0; j < 16; j++) {
        float rv = pvld ? fmaxf(acc[j] + b2[q * 16 + j], 0.f) : 0.f;
#pragma unroll
        for (int sft = 32; sft > 0; sft >>= 1) rv += __shfl_xor(rv, sft);
        if (lane == 0) atomicAdd(&pooled[b * 64 + q * 16 + j], rv);
    }
}

// ---------------- feats = relu(pooled/3136 @ fcf_w + fcf_b) ----------------
__global__ __launch_bounds__(256) void k_fcf(const float* __restrict__ pooled,
                                             const float* __restrict__ w,
                                             const float* __restrict__ bias,
                                             float* __restrict__ feats) {
    int b = blockIdx.x;
    int f0 = threadIdx.x;
    float acc[4];
#pragma unroll
    for (int j = 0; j < 4; j++) acc[j] = bias[f0 + j * 256];
    for (int c = 0; c < 64; c++) {
        float pv = pooled[b * 64 + c] * (1.f / 3136.f);
#pragma unroll
        for (int j = 0; j < 4; j++)
            acc[j] = fmaf(pv, w[c * 1024 + f0 + j * 256], acc[j]);
    }
#pragma unroll
    for (int j = 0; j < 4; j++)
        feats[b * 1024 + f0 + j * 256] = fmaxf(acc[j], 0.f);
}

// ---------------- logits partials: lp[fc][b][c] over f-chunk of 256 ----------------
__global__ __launch_bounds__(128) void k_fcclog(const float* __restrict__ feats,
                                                const float* __restrict__ w,
                                                const float* __restrict__ bias,
                                                float* __restrict__ lp) {
    int b = blockIdx.x, fc = blockIdx.y, c = threadIdx.x;
    if (c >= 80) return;
    float acc = (fc == 0) ? bias[c] : 0.f;
    const f32x4* fv = (const f32x4*)(feats + (size_t)b * 1024 + fc * 256);
    for (int f4 = 0; f4 < 64; f4++) {
        f32x4 fr = fv[f4];                                      // uniform -> s_load
        int f = fc * 256 + f4 * 4;
#pragma unroll
        for (int j = 0; j < 4; j++) acc = fmaf(fr[j], w[(f + j) * 80 + c], acc);
    }
    lp[(fc * 64 + b) * 80 + c] = acc;
}

// ---------------- top2 (JAX tie-break: lower index first) ----------------
__global__ __launch_bounds__(128) void k_top2(const float* __restrict__ lp,
                                              int* __restrict__ top_idx) {
    int b = blockIdx.x, c = threadIdx.x;
    __shared__ float sl[80];
    if (c < 80) {
        float s = 0.f;
#pragma unroll
        for (int fc = 0; fc < 4; fc++) s += lp[(fc * 64 + b) * 80 + c];
        sl[c] = s;
    }
    __syncthreads();
    if (c == 0) {
        int i1 = 0; float v1 = sl[0];
        for (int i = 1; i < 80; i++)
            if (sl[i] > v1) { v1 = sl[i]; i1 = i; }
        int i2 = -1; float v2 = 0.f;
        for (int i = 0; i < 80; i++) {
            if (i == i1) continue;
            if (i2 < 0 || sl[i] > v2) { v2 = sl[i]; i2 = i; }
        }
        top_idx[b * 2] = i1;
        top_idx[b * 2 + 1] = i2;
    }
}

// ---------------- 5-node graph: d2 via quarter norms/dots -> knn -> An, cm ----------------
__global__ __launch_bounds__(256) void k_graph(const float* __restrict__ feats,
                                               float* __restrict__ An,
                                               float* __restrict__ cm,
                                               int* __restrict__ dropped) {
    int b = blockIdx.x;
    int t = threadIdx.x;
    const float* fb = feats + (size_t)b * 1024;
    float q1 = fb[t], q2 = fb[256 + t], q3 = fb[512 + t], q4 = fb[768 + t];
    float part[10] = {q1 * q1, q2 * q2, q3 * q3, q4 * q4,
                      q1 * q2, q1 * q3, q1 * q4, q2 * q3, q2 * q4, q3 * q4};
    __shared__ float sr[10][4];
    int lane = t & 63, wid = t >> 6;
#pragma unroll
    for (int i = 0; i < 10; i++) {
        float r = part[i];
#pragma unroll
        for (int s = 32; s > 0; s >>= 1) r += __shfl_xor(r, s);
        if (lane == 0) sr[i][wid] = r;
    }
    __syncthreads();
    if (t == 0) {
        float tot[10];
#pragma unroll
        for (int i = 0; i < 10; i++) tot[i] = sr[i][0] + sr[i][1] + sr[i][2] + sr[i][3];
        float n_[5] = {0.f, tot[0], tot[1], tot[2], tot[3]};
        float dd[5][5];
        dd[1][1] = tot[0]; dd[2][2] = tot[1]; dd[3][3] = tot[2]; dd[4][4] = tot[3];
        dd[1][2] = dd[2][1] = tot[4]; dd[1][3] = dd[3][1] = tot[5];
        dd[1][4] = dd[4][1] = tot[6]; dd[2][3] = dd[3][2] = tot[7];
        dd[2][4] = dd[4][2] = tot[8]; dd[3][4] = dd[4][3] = tot[9];
        float Q = tot[0] + tot[1] + tot[2] + tot[3];
        float d2[5][5];
        d2[0][0] = 0.f;
        for (int i = 1; i < 5; i++) {
            float v = Q + n_[i] - 2.f * dd[1][i];
            d2[0][i] = v; d2[i][0] = v;
        }
        for (int i = 1; i < 5; i++)
            for (int j = 1; j < 5; j++)
                d2[i][j] = (i == j) ? 0.f : (n_[i] + n_[j] - 2.f * dd[i][j]);
        int drp[5];
        for (int r = 0; r < 5; r++) {
            int dm = 0; float vm = d2[r][0];
            for (int s = 1; s < 5; s++)
                if (d2[r][s] >= vm) { vm = d2[r][s]; dm = s; }
            drp[r] = dm;
            dropped[b * 5 + r] = dm;
        }
        float Ah[5][5], dinv[5];
        for (int r = 0; r < 5; r++) {
            float dsum = 0.f;
            for (int s = 0; s < 5; s++) {
                float a = ((s != drp[r]) ? 1.f : 0.f) + ((s == r) ? 1.f : 0.f);
                Ah[r][s] = a; dsum += a;
            }
            dinv[r] = dsum > 0.f ? 1.f / sqrtf(dsum) : 0.f;
        }
        float colsum[5] = {0.f, 0.f, 0.f, 0.f, 0.f};
        for (int r = 0; r < 5; r++)
            for (int s = 0; s < 5; s++) {
                float v = Ah[r][s] * dinv[r] * dinv[s];
                An[b * 25 + r * 5 + s] = v;
                colsum[s] += v;
            }
        for (int s = 0; s < 5; s++) cm[b * 5 + s] = colsum[s] * 0.2f;
    }
}

// ---------------- agg = An @ Xg ----------------
__global__ __launch_bounds__(256) void k_agg(const float* __restrict__ feats,
                                             const float* __restrict__ An,
                                             float* __restrict__ agg) {
    int b = blockIdx.x;
    __shared__ float sAn[25];
    if (threadIdx.x < 25) sAn[threadIdx.x] = An[b * 25 + threadIdx.x];
    __syncthreads();
    const float* fb = feats + (size_t)b * 1024;
    for (int f = threadIdx.x; f < 1024; f += 256) {
        float a0 = fb[f];
        bool inq = f < 256;
        float v1 = 0.f, v2 = 0.f, v3 = 0.f, v4 = 0.f;
        if (inq) { v1 = fb[f]; v2 = fb[256 + f]; v3 = fb[512 + f]; v4 = fb[768 + f]; }
#pragma unroll
        for (int t = 0; t < 5; t++) {
            float r = sAn[t * 5] * a0;
            if (inq)
                r += sAn[t * 5 + 1] * v1 + sAn[t * 5 + 2] * v2 +
                     sAn[t * 5 + 3] * v3 + sAn[t * 5 + 4] * v4;
            agg[((size_t)b * 5 + t) * 1024 + f] = r;
        }
    }
}

// ---------------- expert layer1 partials over f-chunk: h1part[fc][pair][t][h] ----------------
__global__ __launch_bounds__(128) void k_h1p(const float* __restrict__ agg,
                                             const float* __restrict__ w1,
                                             const int* __restrict__ top_idx,
                                             float* __restrict__ h1part) {
    int pair = blockIdx.x;              // 128
    int fc = blockIdx.y;                // 8 chunks of 128 f
    int hg = threadIdx.x;               // h = 4*hg
    int bsm = pair >> 1;
    int c = top_idx[pair];
    const f32x4* wv = (const f32x4*)(w1 + (size_t)c * 1024 * 512);  // f-row stride 128 (x4)
    const f32x4* av = (const f32x4*)(agg + (size_t)bsm * 5 * 1024); // t-row stride 256 (x4)
    f32x4 acc[5];
#pragma unroll
    for (int t = 0; t < 5; t++) acc[t] = (f32x4)(0.f);
    int f0 = fc * 128;
#pragma unroll 2
    for (int f4 = 0; f4 < 32; f4++) {
        f32x4 a[5];
#pragma unroll
        for (int t = 0; t < 5; t++) a[t] = av[t * 256 + fc * 32 + f4];  // uniform -> s_load
#pragma unroll
        for (int j = 0; j < 4; j++) {
            f32x4 w = wv[(size_t)(f0 + f4 * 4 + j) * 128 + hg];         // 16B coalesced
#pragma unroll
            for (int t = 0; t < 5; t++) acc[t] += a[t][j] * w;
        }
    }
    float* op = h1part + (((size_t)fc * 128 + pair) * 5) * 512;
#pragma unroll
    for (int t = 0; t < 5; t++)
        *(f32x4*)(op + t * 512 + 4 * hg) = acc[t];
}

// ---------------- fold partials: p[pair][h] = sum_t cm[t]*relu(sum_fc part + b1) ----------------
__global__ __launch_bounds__(512) void k_pfold(const float* __restrict__ h1part,
                                               const float* __restrict__ b1,
                                               const float* __restrict__ cm,
                                               const int* __restrict__ top_idx,
                                               float* __restrict__ p) {
    int pair = blockIdx.x;
    int h = threadIdx.x;
    int bsm = pair >> 1;
    int c = top_idx[pair];
    float pv = 0.f;
#pragma unroll
    for (int t = 0; t < 5; t++) {
        float s = 0.f;
#pragma unroll
        for (int fc = 0; fc < 8; fc++)
            s += h1part[(((size_t)fc * 128 + pair) * 5 + t) * 512 + h];
        float hv = fmaxf(s + b1[c * 512 + h], 0.f);
        pv = fmaf(cm[bsm * 5 + t], hv, pv);
    }
    p[pair * 512 + h] = pv;
}

// ---------------- expert layer2 partials: gpart[hc][pair][o] ----------------
__global__ __launch_bounds__(64) void k_gpart(const float* __restrict__ p,
                                              const float* __restrict__ w2,
                                              const int* __restrict__ top_idx,
                                              float* __restrict__ gpart) {
    int pair = blockIdx.x, hc = blockIdx.y;   // 8 chunks of 64 h
    int og = threadIdx.x;                     // o = 4*og
    int c = top_idx[pair];
    const f32x4* wv = (const f32x4*)(w2 + (size_t)c * 512 * 256);  // h-row stride 64 (x4)
    const float* pp = p + pair * 512 + hc * 64;
    f32x4 acc = (f32x4)(0.f);
#pragma unroll 4
    for (int h = 0; h < 64; h++)
        acc += pp[h] * wv[(size_t)(hc * 64 + h) * 64 + og];        // pp[h] uniform
    *(f32x4*)(gpart + ((size_t)hc * 128 + pair) * 256 + 4 * og) = acc;
}

// ---------------- fold g + bias, then M = g @ fin_w ----------------
__global__ __launch_bounds__(256) void k_Mfold(const float* __restrict__ gpart,
                                               const float* __restrict__ b2,
                                               const float* __restrict__ finw,
                                               const int* __restrict__ top_idx,
                                               float* __restrict__ M) {
    __shared__ float sgg[256];
    int n = blockIdx.x, t = threadIdx.x;
    int c = top_idx[n];
    float gg = b2[c * 256 + t];
#pragma unroll
    for (int hc = 0; hc < 8; hc++) gg += gpart[((size_t)hc * 128 + n) * 256 + t];
    sgg[t] = gg;
    __syncthreads();
    if (t < 80) {
        float acc = 0.f;
        for (int o = 0; o < 256; o++) acc = fmaf(sgg[o], finw[o * 80 + t], acc);
        M[n * 80 + t] = acc;
    }
}

// ---------------- final GCN + mean over k ----------------
__global__ __launch_bounds__(128) void k_out(const float* __restrict__ M,
                                             const float* __restrict__ finb,
                                             const int* __restrict__ dropped,
                                             float* __restrict__ out) {
    int b = blockIdx.x;
    int c = threadIdx.x;
    if (c >= 80) return;
    float bias = finb[c];
    float r = 0.f;
#pragma unroll
    for (int k = 0; k < 2; k++) {
        int n = b * 2 + k;
        float fin;
        if (n < 5) {
            float s = 0.f;
            for (int m = 0; m < 5; m++) {
                float a = ((m != dropped[63 * 5 + n]) ? 1.f : 0.f) + ((m == n) ? 1.f : 0.f);
                s += a * M[m * 80 + c];
            }
            fin = s * 0.2f + bias;
        } else {
            fin = M[n * 80 + c] + bias;
        }
        r += fin;
    }
    out[b * 80 + c] = r * 0.5f;
}

extern "C" void kernel_launch(void* const* d_in, const int* in_sizes, int n_in,
                              void* d_out, int out_size, void* d_ws, size_t ws_size,
                              hipStream_t stream) {
    const float* x       = (const float*)d_in[0];
    const float* conv1_w = (const float*)d_in[1];
    const float* conv1_b = (const float*)d_in[2];
    const float* conv2_w = (const float*)d_in[3];
    const float* conv2_b = (const float*)d_in[4];
    const float* fcf_w   = (const float*)d_in[5];
    const float* fcf_b   = (const float*)d_in[6];
    const float* fcc_w   = (const float*)d_in[7];
    const float* fcc_b   = (const float*)d_in[8];
    const float* gnn_w1  = (const float*)d_in[9];
    const float* gnn_b1  = (const float*)d_in[10];
    const float* gnn_w2  = (const float*)d_in[11];
    const float* gnn_b2  = (const float*)d_in[12];
    const float* fin_w   = (const float*)d_in[13];
    const float* fin_b   = (const float*)d_in[14];
    float* out = (float*)d_out;

    char* ws = (char*)d_ws;
    size_t off = 0;
    auto alloc = [&](size_t bytes) {
        void* pp = ws + off;
        off = (off + bytes + 255) & ~(size_t)255;
        return pp;
    };
    float* wt1     = (float*)alloc(864 * 4);
    float* wt2     = (float*)alloc(18432 * 4);
    float* pooled  = (float*)alloc(4096 * 4);
    float* feats   = (float*)alloc(65536 * 4);
    float* lp      = (float*)alloc(20480 * 4);
    int*   top_idx = (int*)alloc(128 * 4);
    float* An      = (float*)alloc(1600 * 4);
    float* cm      = (float*)alloc(320 * 4);
    int*   dropped = (int*)alloc(320 * 4);
    float* agg     = (float*)alloc(327680 * 4);
    float* h1part  = (float*)alloc((size_t)2621440 * 4);   // 8*128*5*512
    float* p       = (float*)alloc(65536 * 4);
    float* gpart   = (float*)alloc(262144 * 4);            // 8*128*256
    float* Mm      = (float*)alloc(10240 * 4);
    (void)ws_size; (void)in_sizes; (void)n_in; (void)out_size;

    k_prep<<<72, 256, 0, stream>>>(conv1_w, conv2_w, wt1, wt2, pooled);
    k_convfused<<<dim3(56, 64), 256, 0, stream>>>(x, wt1, conv1_b, wt2, conv2_b, pooled);
    k_fcf<<<64, 256, 0, stream>>>(pooled, fcf_w, fcf_b, feats);
    k_fcclog<<<dim3(64, 4), 128, 0, stream>>>(feats, fcc_w, fcc_b, lp);
    k_top2<<<64, 128, 0, stream>>>(lp, top_idx);
    k_graph<<<64, 256, 0, stream>>>(feats, An, cm, dropped);
    k_agg<<<64, 256, 0, stream>>>(feats, An, agg);
    k_h1p<<<dim3(128, 8), 128, 0, stream>>>(agg, gnn_w1, top_idx, h1part);
    k_pfold<<<128, 512, 0, stream>>>(h1part, gnn_b1, cm, top_idx, p);
    k_gpart<<<dim3(128, 8), 64, 0, stream>>>(p, gnn_w2, top_idx, gpart);
    k_Mfold<<<128, 256, 0, stream>>>(gpart, gnn_b2, fin_w, top_idx, Mm);
    k_out<<<64, 128, 0, stream>>>(Mm, fin_b, dropped, out);
}

// Round 4
// 650.524 us; speedup vs baseline: 1.3442x; 1.3442x over previous
//
#include <hip/hip_runtime.h>

// YOLO_GNN on MI355X — round 4: low-VGPR fused conv (batched tap loads, float2
// LDS reads) + fully fused tail (5 launches total).
// prep -> convfused -> mid(feats/logits/top2/graph/agg) -> expert(l1+fold+l2+M) -> out.

typedef float f32x4 __attribute__((ext_vector_type(4)));

// ---------------- prep: zero pooled; transpose conv weights ----------------
// wt1: [ci*9 + ky*3 + kx][co32]; wt2: [ky][ci][kx][co64]
__global__ void k_prep(const float* __restrict__ w1, const float* __restrict__ w2,
                       float* __restrict__ wt1, float* __restrict__ wt2,
                       float* __restrict__ pooled) {
    int i = blockIdx.x * 256 + threadIdx.x;
    if (i < 4096) pooled[i] = 0.f;
    if (i < 864) {            // conv1: 32 co x 27 k
        int k = i >> 5, co = i & 31;
        wt1[i] = w1[co * 27 + k];
    }
    if (i < 18432) {          // conv2: ((ky*32+ci)*3+kx)*64+co
        int co = i & 63, tt = i >> 6;
        int kx = tt % 3, u = tt / 3;
        int ci = u & 31, ky = u >> 5;
        wt2[i] = w2[co * 288 + ci * 9 + ky * 3 + kx];
    }
}

// ---------------- fused conv1+ReLU -> LDS -> conv2+ReLU -> GAP ----------------
// Block = one conv2 row (oy) of image b; 256 threads = 4 waves.
// LDS layout s[ci][ky][half][par]: conv1 pixel px -> half=px>>1, par=px&1, so
// conv2's ix=2*opx+kx reads are a float2 (kx=0,1) + one float (kx=2).
__global__ __launch_bounds__(256) void k_convfused(const float* __restrict__ x,
                                                   const float* __restrict__ wt1,
                                                   const float* __restrict__ b1,
                                                   const float* __restrict__ wt2,
                                                   const float* __restrict__ b2,
                                                   float* __restrict__ pooled) {
    __shared__ float s[32][3][57][2];   // 43776 B
    int oy = blockIdx.x;                // 0..55
    int b = blockIdx.y;                 // 0..63
    const float* xb = x + (size_t)b * 3 * 224 * 224;
    int tid = threadIdx.x;

    // ---- stage conv1 rows iy = 2oy..2oy+2, px = 0..113 (112/113 -> zero) ----
#pragma unroll 1
    for (int pr = tid; pr < 342; pr += 256) {
        int r = pr / 114, px = pr % 114;
        int iy = 2 * oy + r;
        if (iy < 112 && px < 112) {
            float acc[32];
#pragma unroll
            for (int j = 0; j < 32; j++) acc[j] = 0.f;
#pragma unroll
            for (int ci = 0; ci < 3; ci++) {
                float xv[9];                           // 9 independent loads
#pragma unroll
                for (int ky = 0; ky < 3; ky++) {
                    int yy = 2 * iy + ky;
#pragma unroll
                    for (int kx = 0; kx < 3; kx++) {
                        int xx = 2 * px + kx;
                        bool ok = (yy < 224) && (xx < 224);   // SAME: pad hi only
                        xv[ky * 3 + kx] = ok ? xb[((size_t)ci * 224 + yy) * 224 + xx] : 0.f;
                    }
                }
#pragma unroll
                for (int k9 = 0; k9 < 9; k9++) {
                    const float* w = wt1 + (ci * 9 + k9) * 32;   // uniform -> s_load
#pragma unroll
                    for (int j = 0; j < 32; j++) acc[j] = fmaf(xv[k9], w[j], acc[j]);
                }
            }
#pragma unroll
            for (int j = 0; j < 32; j++)
                s[j][r][px >> 1][px & 1] = fmaxf(acc[j] + b1[j], 0.f);
        } else {
#pragma unroll
            for (int j = 0; j < 32; j++)
                s[j][r][px >> 1][px & 1] = 0.f;
        }
    }
    __syncthreads();

    // ---- conv2: wave q -> co [16q,16q+16); lane -> opx ----
    int q = __builtin_amdgcn_readfirstlane((int)(tid >> 6));
    int lane = tid & 63;
    bool pvld = lane < 56;
    int opx = pvld ? lane : 55;
    float acc[16];
#pragma unroll
    for (int j = 0; j < 16; j++) acc[j] = 0.f;
#pragma unroll
    for (int ky = 0; ky < 3; ky++) {
#pragma unroll 4
        for (int ci = 0; ci < 32; ci++) {
            float2 v01 = *(const float2*)&s[ci][ky][opx][0];     // kx=0,1
            float v2 = s[ci][ky][opx + 1][0];                    // kx=2
            const float* w = wt2 + ((ky * 32 + ci) * 3) * 64 + q * 16;  // uniform
#pragma unroll
            for (int j = 0; j < 16; j++) acc[j] = fmaf(v01.x, w[j], acc[j]);
#pragma unroll
            for (int j = 0; j < 16; j++) acc[j] = fmaf(v01.y, w[64 + j], acc[j]);
#pragma unroll
            for (int j = 0; j < 16; j++) acc[j] = fmaf(v2, w[128 + j], acc[j]);
        }
    }
#pragma unroll
    for (int j = 0; j < 16; j++) {
        float rv = pvld ? fmaxf(acc[j] + b2[q * 16 + j], 0.f) : 0.f;
#pragma unroll
        for (int sft = 32; sft > 0; sft >>= 1) rv += __shfl_xor(rv, sft);
        if (lane == 0) atomicAdd(&pooled[b * 64 + q * 16 + j], rv);
    }
}

// ---------------- mid: feats -> logits -> top2 -> graph(An,cm,dropped) -> agg ----------------
// One block per sample b; feats/An live only in LDS.
__global__ __launch_bounds__(256) void k_mid(const float* __restrict__ pooled,
                                             const float* __restrict__ fcf_w,
                                             const float* __restrict__ fcf_b,
                                             const float* __restrict__ fcc_w,
                                             const float* __restrict__ fcc_b,
                                             int* __restrict__ top_idx,
                                             float* __restrict__ cm,
                                             int* __restrict__ dropped,
                                             float* __restrict__ agg) {
    __shared__ float sf[1024];
    __shared__ float slog[2][80];
    __shared__ float sr[10][4];
    __shared__ float sAn[25];
    int b = blockIdx.x, t = threadIdx.x;

    // feats = relu(pooled/3136 @ fcf_w + fcf_b)
    {
        float acc[4];
#pragma unroll
        for (int j = 0; j < 4; j++) acc[j] = fcf_b[t + j * 256];
        for (int cc = 0; cc < 64; cc++) {
            float pv = pooled[b * 64 + cc] * (1.f / 3136.f);    // uniform
#pragma unroll
            for (int j = 0; j < 4; j++)
                acc[j] = fmaf(pv, fcf_w[cc * 1024 + t + j * 256], acc[j]);
        }
#pragma unroll
        for (int j = 0; j < 4; j++) sf[t + j * 256] = fmaxf(acc[j], 0.f);
    }
    __syncthreads();

    // logits halves: t<160: c=t%80, half=t/80 over 512 f each
    if (t < 160) {
        int c = t % 80, half = t / 80;
        float acc = half ? 0.f : fcc_b[c];
        for (int f = half * 512; f < half * 512 + 512; f++)
            acc = fmaf(sf[f], fcc_w[f * 80 + c], acc);          // sf broadcast
        slog[half][c] = acc;
    }
    // graph quarter norms/dots (all 256 threads, independent of logits)
    {
        float q1 = sf[t], q2 = sf[256 + t], q3 = sf[512 + t], q4 = sf[768 + t];
        float part[10] = {q1 * q1, q2 * q2, q3 * q3, q4 * q4,
                          q1 * q2, q1 * q3, q1 * q4, q2 * q3, q2 * q4, q3 * q4};
        int lane = t & 63, wid = t >> 6;
#pragma unroll
        for (int i = 0; i < 10; i++) {
            float r = part[i];
#pragma unroll
            for (int sft = 32; sft > 0; sft >>= 1) r += __shfl_xor(r, sft);
            if (lane == 0) sr[i][wid] = r;
        }
    }
    __syncthreads();

    // top2 over 80 logits: wave 0, lane ln holds c=ln (+ c=64+ln for ln<16)
    if (t < 64) {
        int ln = t;
        float vA = slog[0][ln] + slog[1][ln];
        int iA = ln;
        bool hasB = ln < 16;
        float vB = hasB ? slog[0][64 + ln] + slog[1][64 + ln] : -3.4e38f;
        int iB = hasB ? 64 + ln : 0x7fffffff;
        float v1, v2; int i1, i2;
        if (vB > vA) { v1 = vB; i1 = iB; v2 = vA; i2 = iA; }
        else         { v1 = vA; i1 = iA; v2 = vB; i2 = iB; }
#pragma unroll
        for (int m = 1; m < 64; m <<= 1) {
            float o1 = __shfl_xor(v1, m), o2 = __shfl_xor(v2, m);
            int oi1 = __shfl_xor(i1, m), oi2 = __shfl_xor(i2, m);
            bool selfWins = (v1 > o1) || (v1 == o1 && i1 < oi1);
            float n1, n2; int ni1, ni2;
            if (selfWins) {
                n1 = v1; ni1 = i1;
                bool s2 = (v2 > oi1 * 0.f + o1) || (v2 == o1 && i2 < oi1);
                n2 = s2 ? v2 : o1; ni2 = s2 ? i2 : oi1;
            } else {
                n1 = o1; ni1 = oi1;
                bool s2 = (v1 > o2) || (v1 == o2 && i1 < oi2);
                n2 = s2 ? v1 : o2; ni2 = s2 ? i1 : oi2;
            }
            v1 = n1; i1 = ni1; v2 = n2; i2 = ni2;
        }
        if (ln == 0) { top_idx[b * 2] = i1; top_idx[b * 2 + 1] = i2; }
    }
    // graph: d2 -> knn -> An (LDS), cm, dropped  (thread 0)
    if (t == 0) {
        float tot[10];
#pragma unroll
        for (int i = 0; i < 10; i++) tot[i] = sr[i][0] + sr[i][1] + sr[i][2] + sr[i][3];
        float n_[5] = {0.f, tot[0], tot[1], tot[2], tot[3]};
        float dd[5][5];
        dd[1][1] = tot[0]; dd[2][2] = tot[1]; dd[3][3] = tot[2]; dd[4][4] = tot[3];
        dd[1][2] = dd[2][1] = tot[4]; dd[1][3] = dd[3][1] = tot[5];
        dd[1][4] = dd[4][1] = tot[6]; dd[2][3] = dd[3][2] = tot[7];
        dd[2][4] = dd[4][2] = tot[8]; dd[3][4] = dd[4][3] = tot[9];
        float Q = tot[0] + tot[1] + tot[2] + tot[3];
        float d2[5][5];
        d2[0][0] = 0.f;
        for (int i = 1; i < 5; i++) {
            float v = Q + n_[i] - 2.f * dd[1][i];
            d2[0][i] = v; d2[i][0] = v;
        }
        for (int i = 1; i < 5; i++)
            for (int j = 1; j < 5; j++)
                d2[i][j] = (i == j) ? 0.f : (n_[i] + n_[j] - 2.f * dd[i][j]);
        int drp[5];
        for (int r = 0; r < 5; r++) {
            int dm = 0; float vm = d2[r][0];
            for (int ss = 1; ss < 5; ss++)
                if (d2[r][ss] >= vm) { vm = d2[r][ss]; dm = ss; }
            drp[r] = dm;
            dropped[b * 5 + r] = dm;
        }
        float dinv[5];
        float Ah[5][5];
        for (int r = 0; r < 5; r++) {
            float dsum = 0.f;
            for (int ss = 0; ss < 5; ss++) {
                float a = ((ss != drp[r]) ? 1.f : 0.f) + ((ss == r) ? 1.f : 0.f);
                Ah[r][ss] = a; dsum += a;
            }
            dinv[r] = dsum > 0.f ? 1.f / sqrtf(dsum) : 0.f;
        }
        float colsum[5] = {0.f, 0.f, 0.f, 0.f, 0.f};
        for (int r = 0; r < 5; r++)
            for (int ss = 0; ss < 5; ss++) {
                float v = Ah[r][ss] * dinv[r] * dinv[ss];
                sAn[r * 5 + ss] = v;
                colsum[ss] += v;
            }
        for (int ss = 0; ss < 5; ss++) cm[b * 5 + ss] = colsum[ss] * 0.2f;
    }
    __syncthreads();

    // agg = An @ Xg
    for (int f = t; f < 1024; f += 256) {
        float a0 = sf[f];
        bool inq = f < 256;
        float v1 = 0.f, v2 = 0.f, v3 = 0.f, v4 = 0.f;
        if (inq) { v1 = sf[f]; v2 = sf[256 + f]; v3 = sf[512 + f]; v4 = sf[768 + f]; }
#pragma unroll
        for (int tt = 0; tt < 5; tt++) {
            float r = sAn[tt * 5] * a0;
            if (inq)
                r += sAn[tt * 5 + 1] * v1 + sAn[tt * 5 + 2] * v2 +
                     sAn[tt * 5 + 3] * v3 + sAn[tt * 5 + 4] * v4;
            agg[((size_t)b * 5 + tt) * 1024 + f] = r;
        }
    }
}

// ---------------- expert: layer1 + mean-fold + layer2 + @fin_w, one block per pair -----------
__global__ __launch_bounds__(256) void k_expert(const float* __restrict__ agg,
                                                const float* __restrict__ w1,
                                                const float* __restrict__ b1,
                                                const float* __restrict__ w2,
                                                const float* __restrict__ b2,
                                                const float* __restrict__ finw,
                                                const float* __restrict__ cm,
                                                const int* __restrict__ top_idx,
                                                float* __restrict__ M) {
    __shared__ float part[2 * 5 * 512];   // 20 KB: [fh][t][h]
    __shared__ float sp[512];
    __shared__ float sgq[4 * 256];        // [hq][o] partials
    __shared__ float sgg[256];
    int pair = blockIdx.x, t = threadIdx.x;
    int bsm = pair >> 1;
    int c = top_idx[pair];

    // layer 1: thread (hg=t&127, fh=t>>7) accumulates f32x4 over its f-half
    {
        int hg = t & 127, fh = t >> 7;
        const f32x4* wv = (const f32x4*)(w1 + (size_t)c * 1024 * 512);
        const f32x4* av = (const f32x4*)(agg + (size_t)bsm * 5 * 1024);
        f32x4 acc[5];
#pragma unroll
        for (int tt = 0; tt < 5; tt++) acc[tt] = (f32x4)(0.f);
#pragma unroll 2
        for (int f4 = 0; f4 < 128; f4++) {
            f32x4 a[5];
#pragma unroll
            for (int tt = 0; tt < 5; tt++) a[tt] = av[tt * 256 + fh * 128 + f4];  // uniform
            int fbase = fh * 512 + f4 * 4;
#pragma unroll
            for (int j = 0; j < 4; j++) {
                f32x4 w = wv[(size_t)(fbase + j) * 128 + hg];   // 16B coalesced
#pragma unroll
                for (int tt = 0; tt < 5; tt++) acc[tt] += a[tt][j] * w;
            }
        }
#pragma unroll
        for (int tt = 0; tt < 5; tt++)
            *(f32x4*)&part[(fh * 5 + tt) * 512 + 4 * hg] = acc[tt];
    }
    __syncthreads();

    // fold: p[h] = sum_t cm[t]*relu(part0+part1 + b1)
#pragma unroll
    for (int rep = 0; rep < 2; rep++) {
        int h = t + rep * 256;
        float pv = 0.f;
#pragma unroll
        for (int tt = 0; tt < 5; tt++) {
            float sv = part[(0 * 5 + tt) * 512 + h] + part[(1 * 5 + tt) * 512 + h];
            float hv = fmaxf(sv + b1[c * 512 + h], 0.f);
            pv = fmaf(cm[bsm * 5 + tt], hv, pv);
        }
        sp[h] = pv;
    }
    __syncthreads();

    // layer 2: thread (og=t&63, hq=t>>6): f32x4 over its h-quarter
    {
        int og = t & 63, hq = t >> 6;
        const f32x4* wv2 = (const f32x4*)(w2 + (size_t)c * 512 * 256);
        f32x4 acc2 = (f32x4)(0.f);
#pragma unroll 4
        for (int h = hq * 128; h < hq * 128 + 128; h++)
            acc2 += sp[h] * wv2[(size_t)h * 64 + og];            // sp broadcast
        *(f32x4*)&sgq[(hq * 64 + og) * 4] = acc2;
    }
    __syncthreads();
    if (t < 64) {
        f32x4 gsum = *(const f32x4*)&sgq[(0 * 64 + t) * 4];
#pragma unroll
        for (int hq = 1; hq < 4; hq++) gsum += *(const f32x4*)&sgq[(hq * 64 + t) * 4];
        gsum += *(const f32x4*)&b2[c * 256 + 4 * t];
        *(f32x4*)&sgg[4 * t] = gsum;
    }
    __syncthreads();
    // M[pair] = g @ fin_w
    if (t < 80) {
        float acc3 = 0.f;
        for (int o = 0; o < 256; o++) acc3 = fmaf(sgg[o], finw[o * 80 + t], acc3);
        M[pair * 80 + t] = acc3;
    }
}

// ---------------- final GCN + mean over k ----------------
__global__ __launch_bounds__(128) void k_out(const float* __restrict__ M,
                                             const float* __restrict__ finb,
                                             const int* __restrict__ dropped,
                                             float* __restrict__ out) {
    int b = blockIdx.x;
    int c = threadIdx.x;
    if (c >= 80) return;
    float bias = finb[c];
    float r = 0.f;
#pragma unroll
    for (int k = 0; k < 2; k++) {
        int n = b * 2 + k;
        float fin;
        if (n < 5) {
            float s = 0.f;
            for (int m = 0; m < 5; m++) {
                float a = ((m != dropped[63 * 5 + n]) ? 1.f : 0.f) + ((m == n) ? 1.f : 0.f);
                s += a * M[m * 80 + c];
            }
            fin = s * 0.2f + bias;
        } else {
            fin = M[n * 80 + c] + bias;
        }
        r += fin;
    }
    out[b * 80 + c] = r * 0.5f;
}

extern "C" void kernel_launch(void* const* d_in, const int* in_sizes, int n_in,
                              void* d_out, int out_size, void* d_ws, size_t ws_size,
                              hipStream_t stream) {
    const float* x       = (const float*)d_in[0];
    const float* conv1_w = (const float*)d_in[1];
    const float* conv1_b = (const float*)d_in[2];
    const float* conv2_w = (const float*)d_in[3];
    const float* conv2_b = (const float*)d_in[4];
    const float* fcf_w   = (const float*)d_in[5];
    const float* fcf_b   = (const float*)d_in[6];
    const float* fcc_w   = (const float*)d_in[7];
    const float* fcc_b   = (const float*)d_in[8];
    const float* gnn_w1  = (const float*)d_in[9];
    const float* gnn_b1  = (const float*)d_in[10];
    const float* gnn_w2  = (const float*)d_in[11];
    const float* gnn_b2  = (const float*)d_in[12];
    const float* fin_w   = (const float*)d_in[13];
    const float* fin_b   = (const float*)d_in[14];
    float* out = (float*)d_out;

    char* ws = (char*)d_ws;
    size_t off = 0;
    auto alloc = [&](size_t bytes) {
        void* pp = ws + off;
        off = (off + bytes + 255) & ~(size_t)255;
        return pp;
    };
    float* wt1     = (float*)alloc(864 * 4);
    float* wt2     = (float*)alloc(18432 * 4);
    float* pooled  = (float*)alloc(4096 * 4);
    int*   top_idx = (int*)alloc(128 * 4);
    float* cm      = (float*)alloc(320 * 4);
    int*   dropped = (int*)alloc(320 * 4);
    float* agg     = (float*)alloc(327680 * 4);
    float* Mm      = (float*)alloc(10240 * 4);
    (void)ws_size; (void)in_sizes; (void)n_in; (void)out_size;

    k_prep<<<72, 256, 0, stream>>>(conv1_w, conv2_w, wt1, wt2, pooled);
    k_convfused<<<dim3(56, 64), 256, 0, stream>>>(x, wt1, conv1_b, wt2, conv2_b, pooled);
    k_mid<<<64, 256, 0, stream>>>(pooled, fcf_w, fcf_b, fcc_w, fcc_b,
                                  top_idx, cm, dropped, agg);
    k_expert<<<128, 256, 0, stream>>>(agg, gnn_w1, gnn_b1, gnn_w2, gnn_b2,
                                      fin_w, cm, top_idx, Mm);
    k_out<<<64, 128, 0, stream>>>(Mm, fin_b, dropped, out);
}